// Round 6
// baseline (322.873 us; speedup 1.0000x reference)
//
#include <hip/hip_runtime.h>

#define B_ 2
#define C_ 3
#define H_ 512
#define W_ 512
#define F_ 5
#define T_ 25
#define HW_ (H_ * W_)

typedef float v2f __attribute__((ext_vector_type(2)));

// Repack planar [B][C][H][W] -> pixel-packed [B][H][W][4] (w component = 0).
__global__ __launch_bounds__(256) void repack_kernel(
    const float* __restrict__ inp, float4* __restrict__ pk)
{
    const int idx = blockIdx.x * blockDim.x + threadIdx.x;   // over B*H*W, exact
    const int hw = idx & (HW_ - 1);
    const int b  = idx >> 18;
    const float* p = inp + b * (C_ * HW_) + hw;
    float4 v;
    v.x = p[0];
    v.y = p[HW_];
    v.z = p[2 * HW_];
    v.w = 0.0f;
    pk[idx] = v;
}

// Block = 256 threads = 4 waves. Wave lanes cover 64 consecutive w-pairs
// (128 w), waves cover 4 consecutive h rows -> block tile 128w x 4h.
// Each thread computes 2 output pixels (w0, w0+1): float2 streaming loads
// (512B/wave/instr) + two independent dependency chains per wave.
__global__ __launch_bounds__(256) void dsepconv_kernel(
    const float4* __restrict__ pk,   // packed input [B][H][W][4]
    const float* __restrict__ vert,
    const float* __restrict__ horz,
    const float* __restrict__ offx,
    const float* __restrict__ offy,
    const float* __restrict__ mask,
    float* __restrict__ out)
{
    const int tx   = threadIdx.x;
    const int lane = tx & 63;
    const int h    = (blockIdx.y << 2) + (tx >> 6);
    const int w0   = (blockIdx.x << 7) + (lane << 1);
    const int b    = blockIdx.z;

    const int hw = (h << 9) | w0;

    const float2* vb   = (const float2*)(vert + b * (F_ * HW_) + hw);
    const float2* hb   = (const float2*)(horz + b * (F_ * HW_) + hw);
    const float2* ob_x = (const float2*)(offx + b * (T_ * HW_) + hw);
    const float2* ob_y = (const float2*)(offy + b * (T_ * HW_) + hw);
    const float2* mb   = (const float2*)(mask + b * (T_ * HW_) + hw);
    const float4* pb   = pk + b * HW_;

    float2 v[F_], hz[F_];
#pragma unroll
    for (int f = 0; f < F_; ++f) v[f]  = vb[f * (HW_ / 2)];
#pragma unroll
    for (int f = 0; f < F_; ++f) hz[f] = hb[f * (HW_ / 2)];

    float acc[2][3] = {{0.f,0.f,0.f},{0.f,0.f,0.f}};

    const float hf = (float)h;
    const float wfp[2] = { (float)w0, (float)(w0 + 1) };

    // ---- software pipeline over fy rows: prefetch row fy+1 while computing fy ----
    float2 cy[F_], cx[F_], cm[F_];
#pragma unroll
    for (int fx = 0; fx < F_; ++fx) {
        cy[fx] = ob_y[fx * (HW_ / 2)];
        cx[fx] = ob_x[fx * (HW_ / 2)];
        cm[fx] = mb  [fx * (HW_ / 2)];
    }

#pragma unroll
    for (int fy = 0; fy < F_; ++fy) {
        float2 ny[F_], nx[F_], nm[F_];
        if (fy < F_ - 1) {
#pragma unroll
            for (int fx = 0; fx < F_; ++fx) {
                const int t = (fy + 1) * F_ + fx;
                ny[fx] = ob_y[t * (HW_ / 2)];
                nx[fx] = ob_x[t * (HW_ / 2)];
                nm[fx] = mb  [t * (HW_ / 2)];
            }
        }

        const float fyf = (float)fy;

#pragma unroll
        for (int fx = 0; fx < F_; ++fx) {
#pragma unroll
            for (int p = 0; p < 2; ++p) {
                const float oy = p ? cy[fx].y : cy[fx].x;
                const float ox = p ? cx[fx].y : cx[fx].x;
                const float m  = p ? cm[fx].y : cm[fx].x;
                const float vf = p ? v[fy].y  : v[fy].x;
                const float hf2= p ? hz[fx].y : hz[fx].x;

                // Exact simplification (W=H=512):
                //   ix = clamp(oy + w + fx - 1.5, -0.5, W-0.5)
                // faithful to reference: x uses offset_y, y uses offset_x
                float ixf = oy + (wfp[p] + (float)fx - 1.5f);
                float iyf = ox + (hf     + fyf       - 1.5f);
                ixf = fminf(fmaxf(ixf, -0.5f), (float)W_ - 0.5f);
                iyf = fminf(fmaxf(iyf, -0.5f), (float)H_ - 0.5f);

                float x0f = floorf(ixf), y0f = floorf(iyf);
                float wx1 = ixf - x0f,   wy1 = iyf - y0f;
                float wx0 = 1.0f - wx1,  wy0 = 1.0f - wy1;

                int x0 = min(max((int)x0f, 0), W_ - 1);
                int x1 = min(max((int)x0f + 1, 0), W_ - 1);
                int y0 = min(max((int)y0f, 0), H_ - 1);
                int y1 = min(max((int)y0f + 1, 0), H_ - 1);

                const float coef = vf * hf2 * m;
                const float c00 = coef * wy0 * wx0;
                const float c01 = coef * wy0 * wx1;
                const float c10 = coef * wy1 * wx0;
                const float c11 = coef * wy1 * wx1;

                const float4 g00 = pb[(y0 << 9) | x0];
                const float4 g01 = pb[(y0 << 9) | x1];
                const float4 g10 = pb[(y1 << 9) | x0];
                const float4 g11 = pb[(y1 << 9) | x1];

                acc[p][0] += c00 * g00.x + c01 * g01.x + c10 * g10.x + c11 * g11.x;
                acc[p][1] += c00 * g00.y + c01 * g01.y + c10 * g10.y + c11 * g11.y;
                acc[p][2] += c00 * g00.z + c01 * g01.z + c10 * g10.z + c11 * g11.z;
            }
        }

        if (fy < F_ - 1) {
#pragma unroll
            for (int fx = 0; fx < F_; ++fx) {
                cy[fx] = ny[fx];
                cx[fx] = nx[fx];
                cm[fx] = nm[fx];
            }
        }
    }

    float* ob = out + b * (C_ * HW_) + hw;
    v2f o0 = { acc[0][0], acc[1][0] };
    v2f o1 = { acc[0][1], acc[1][1] };
    v2f o2 = { acc[0][2], acc[1][2] };
    __builtin_nontemporal_store(o0, (v2f*)ob);
    __builtin_nontemporal_store(o1, (v2f*)(ob + HW_));
    __builtin_nontemporal_store(o2, (v2f*)(ob + 2 * HW_));
}

extern "C" void kernel_launch(void* const* d_in, const int* in_sizes, int n_in,
                              void* d_out, int out_size, void* d_ws, size_t ws_size,
                              hipStream_t stream) {
    const float* inp  = (const float*)d_in[0];
    const float* vert = (const float*)d_in[1];
    const float* horz = (const float*)d_in[2];
    const float* offx = (const float*)d_in[3];
    const float* offy = (const float*)d_in[4];
    const float* mask = (const float*)d_in[5];
    float* out = (float*)d_out;
    float4* pk = (float4*)d_ws;   // B*H*W float4 = 8.4 MB

    const int total = B_ * H_ * W_;
    dim3 block1(256), grid1(total / 256);
    hipLaunchKernelGGL(repack_kernel, grid1, block1, 0, stream, inp, pk);

    dim3 block2(256);
    dim3 grid2(W_ / 128, H_ / 4, B_);
    hipLaunchKernelGGL(dsepconv_kernel, grid2, block2, 0, stream,
                       pk, vert, horz, offx, offy, mask, out);
}

// Round 7
// 207.329 us; speedup vs baseline: 1.5573x; 1.5573x over previous
//
#include <hip/hip_runtime.h>

#define B_ 2
#define C_ 3
#define H_ 512
#define W_ 512
#define F_ 5
#define T_ 25
#define HW_ (H_ * W_)
#define PW_ 520   // packed row stride in pixels (8B each)
#define PH_ 513   // packed rows; row 512 duplicates row 511 (border clamp)

// streaming loads: no reuse
#define NT(p) __builtin_nontemporal_load(p)

typedef _Float16 h4 __attribute__((ext_vector_type(4), aligned(8)));
typedef _Float16 h8 __attribute__((ext_vector_type(8), aligned(8)));

// Repack planar f32 [B][C][H][W] -> fp16x4-packed [B][PH_][PW_] with
// duplicated clamp column (x=512 == x=511) and clamp row (row 512 == 511).
__global__ __launch_bounds__(256) void repack_kernel(
    const float* __restrict__ inp, h4* __restrict__ pk)
{
    const int x   = (blockIdx.x << 8) + threadIdx.x;   // 0..511
    const int row = blockIdx.y;                        // 0..512
    const int b   = blockIdx.z;
    const int sr  = row < H_ ? row : H_ - 1;
    const float* p = inp + b * (C_ * HW_) + (sr << 9) + x;
    h4 v;
    v.x = (_Float16)p[0];
    v.y = (_Float16)p[HW_];
    v.z = (_Float16)p[2 * HW_];
    v.w = (_Float16)0.f;
    h4* dst = pk + b * (PH_ * PW_) + row * PW_;
    dst[x] = v;
    if (x == W_ - 1) dst[W_] = v;   // duplicate clamp column
}

__global__ __launch_bounds__(256) void dsepconv_kernel(
    const h4* __restrict__ pk,       // packed input
    const float* __restrict__ vert,
    const float* __restrict__ horz,
    const float* __restrict__ offx,
    const float* __restrict__ offy,
    const float* __restrict__ mask,
    float* __restrict__ out)
{
    const int idx = blockIdx.x * blockDim.x + threadIdx.x;  // grid is exact
    const int w = idx & (W_ - 1);
    const int h = (idx >> 9) & (H_ - 1);
    const int b = idx >> 18;

    const int hw = (h << 9) | w;

    const float* vb   = vert + b * (F_ * HW_) + hw;
    const float* hb   = horz + b * (F_ * HW_) + hw;
    const float* ob_x = offx + b * (T_ * HW_) + hw;
    const float* ob_y = offy + b * (T_ * HW_) + hw;
    const float* mb   = mask + b * (T_ * HW_) + hw;
    const h4* pb      = pk + b * (PH_ * PW_);

    float v[F_], hz[F_];
#pragma unroll
    for (int f = 0; f < F_; ++f) v[f]  = NT(vb + f * HW_);
#pragma unroll
    for (int f = 0; f < F_; ++f) hz[f] = NT(hb + f * HW_);

    float acc0 = 0.f, acc1 = 0.f, acc2 = 0.f;

    const float wf = (float)w;
    const float hf = (float)h;

    // ---- software pipeline over fy rows: prefetch row fy+1 while computing fy ----
    float cy[F_], cx[F_], cm[F_];
#pragma unroll
    for (int fx = 0; fx < F_; ++fx) {
        cy[fx] = NT(ob_y + fx * HW_);
        cx[fx] = NT(ob_x + fx * HW_);
        cm[fx] = NT(mb   + fx * HW_);
    }

#pragma unroll
    for (int fy = 0; fy < F_; ++fy) {
        float ny[F_], nx[F_], nm[F_];
        if (fy < F_ - 1) {
#pragma unroll
            for (int fx = 0; fx < F_; ++fx) {
                const int t = (fy + 1) * F_ + fx;
                ny[fx] = NT(ob_y + t * HW_);
                nx[fx] = NT(ob_x + t * HW_);
                nm[fx] = NT(mb   + t * HW_);
            }
        }

        const float vfy = v[fy];
        const float fyf = (float)fy;

#pragma unroll
        for (int fx = 0; fx < F_; ++fx) {
            const float oy = cy[fx];
            const float ox = cx[fx];
            const float m  = cm[fx];

            // Exact simplification (W=H=512):
            //   ix = clamp(oy + w + fx - 1.5, -0.5, W-0.5)
            // faithful to reference: x uses offset_y, y uses offset_x
            float ixf = oy + (wf + (float)fx - 1.5f);
            float iyf = ox + (hf + fyf       - 1.5f);
            ixf = fminf(fmaxf(ixf, -0.5f), (float)W_ - 0.5f);
            iyf = fminf(fmaxf(iyf, -0.5f), (float)H_ - 0.5f);

            float x0f = floorf(ixf), y0f = floorf(iyf);
            // When floor==-1 the reference clamps BOTH neighbors to index 0;
            // equivalent to base=0 with all weight on the left/top sample.
            float wx1 = (x0f < 0.f) ? 0.f : (ixf - x0f);
            float wy1 = (y0f < 0.f) ? 0.f : (iyf - y0f);
            float wx0 = 1.0f - wx1;

            const int xb = (int)fmaxf(x0f, 0.f);   // 0..511
            const int yb = (int)fmaxf(y0f, 0.f);   // 0..511 (row yb+1 valid via dup row)

            // two 16B gathers: (pixel xb, xb+1) on rows yb and yb+1
            const h8 gt = *(const h8*)(pb + yb * PW_ + xb);
            const h8 gb = *(const h8*)(pb + (yb + 1) * PW_ + xb);

            const float coef = vfy * hz[fx] * m;
            const float cw0 = coef * (1.0f - wy1);
            const float cw1 = coef * wy1;

            const float t0 = wx0 * (float)gt[0] + wx1 * (float)gt[4];
            const float t1 = wx0 * (float)gt[1] + wx1 * (float)gt[5];
            const float t2 = wx0 * (float)gt[2] + wx1 * (float)gt[6];
            const float b0 = wx0 * (float)gb[0] + wx1 * (float)gb[4];
            const float b1 = wx0 * (float)gb[1] + wx1 * (float)gb[5];
            const float b2 = wx0 * (float)gb[2] + wx1 * (float)gb[6];

            acc0 += cw0 * t0 + cw1 * b0;
            acc1 += cw0 * t1 + cw1 * b1;
            acc2 += cw0 * t2 + cw1 * b2;
        }

        if (fy < F_ - 1) {
#pragma unroll
            for (int fx = 0; fx < F_; ++fx) {
                cy[fx] = ny[fx];
                cx[fx] = nx[fx];
                cm[fx] = nm[fx];
            }
        }
    }

    float* ob = out + b * (C_ * HW_) + hw;
    __builtin_nontemporal_store(acc0, ob);
    __builtin_nontemporal_store(acc1, ob + HW_);
    __builtin_nontemporal_store(acc2, ob + 2 * HW_);
}

extern "C" void kernel_launch(void* const* d_in, const int* in_sizes, int n_in,
                              void* d_out, int out_size, void* d_ws, size_t ws_size,
                              hipStream_t stream) {
    const float* inp  = (const float*)d_in[0];
    const float* vert = (const float*)d_in[1];
    const float* horz = (const float*)d_in[2];
    const float* offx = (const float*)d_in[3];
    const float* offy = (const float*)d_in[4];
    const float* mask = (const float*)d_in[5];
    float* out = (float*)d_out;
    h4* pk = (h4*)d_ws;   // B * 513 * 520 * 8B = 4.27 MB

    dim3 blockR(256), gridR(W_ / 256, PH_, B_);
    hipLaunchKernelGGL(repack_kernel, gridR, blockR, 0, stream, inp, pk);

    const int total = B_ * H_ * W_;
    dim3 block(256), grid(total / 256);
    hipLaunchKernelGGL(dsepconv_kernel, grid, block, 0, stream,
                       pk, vert, horz, offx, offy, mask, out);
}